// Round 8
// baseline (1020.608 us; speedup 1.0000x reference)
//
#include <hip/hip_runtime.h>
#include <hip/hip_bf16.h>

typedef __bf16 bf16;
typedef bf16 bf16x4 __attribute__((ext_vector_type(4)));
typedef bf16 bf16x8 __attribute__((ext_vector_type(8)));
typedef float f32x4 __attribute__((ext_vector_type(4)));

#define MFMA16(a, b, c) __builtin_amdgcn_mfma_f32_16x16x32_bf16((a), (b), (c), 0, 0, 0)

constexpr float kScale = 0.17677669529663687f;  // 1/sqrt(32)

// ---- workspace offsets (bytes) ----
constexpr int WQKV_OFF = 0;        // bf16[768*256]
constexpr int WPROJ_OFF = 393216;  // bf16[256*256]
constexpr int BIAS_OFF = 524288;   // f32[8][49 m][49 n]  (transposed bias)
constexpr int BQKV_OFF = 601120;   // f32[768]

// ---- LDS layout (bytes) ----
// region A: xb bf16 [32 cc][51 n][8] = 26112 B; later proj f32 half [49][128] = 25088 B
// region B: ao bf16 [32 cc][51 n][8] = 26112 B (attn-out; per-wave disjoint chunks)
// + 256 B guard for benign OOB fragment reads
constexpr int A_OFF = 0;
constexpr int B_OFF = 26112;
constexpr int QS = 408;  // 51 rows * 8 (de-banks staging: 8-way -> 4-way)
constexpr int LDS_BYTES = 52480;

__global__ void prep_kernel(const float* __restrict__ w_qkv, const float* __restrict__ b_qkv,
                            const float* __restrict__ w_proj, const float* __restrict__ bias_table,
                            const int* __restrict__ rel_index, char* __restrict__ ws) {
  int i = blockIdx.x * 256 + threadIdx.x;
  bf16* wqkvb = (bf16*)(ws + WQKV_OFF);
  bf16* wprojb = (bf16*)(ws + WPROJ_OFF);
  float* biasx = (float*)(ws + BIAS_OFF);
  float* bqs = (float*)(ws + BQKV_OFF);
  if (i < 196608) {
    float v = w_qkv[i];
    if (i < 65536) v *= kScale;  // q rows (o<256): fold scale
    wqkvb[i] = (bf16)v;
  } else if (i < 262144) {
    int j = i - 196608;
    wprojb[j] = (bf16)w_proj[j];
  } else if (i < 281352) {
    int j = i - 262144;  // 8*2401, layout [h][m][n]
    int h = j / 2401, nm = j - h * 2401;
    int mm = nm / 49, nn = nm - mm * 49;
    biasx[j] = bias_table[rel_index[nn * 49 + mm] * 8 + h];  // bias[h][nn][mm]
  } else if (i < 282120) {
    int j = i - 281352;
    bqs[j] = b_qkv[j] * (j < 256 ? kScale : 1.0f);
  }
}

// Shuffle-transpose: treats (lo,hi) as a 32-row pair; f[j] = Pair[row32=g*8+j][col=c].
__device__ __forceinline__ bf16x8 xpose8(f32x4 lo, f32x4 hi, int base, bool glow) {
  bf16x8 f;
#pragma unroll
  for (int i = 0; i < 4; ++i) {
    float a0 = __shfl(lo[i], base);
    float a1 = __shfl(lo[i], base + 16);
    float b0 = __shfl(hi[i], base);
    float b1 = __shfl(hi[i], base + 16);
    f[i] = (bf16)(glow ? a0 : b0);
    f[i + 4] = (bf16)(glow ? a1 : b1);
  }
  return f;
}

// Two 16-row weight tiles, D[o][n] (A=W, B=X): acc2[tf][nt] += bias
__device__ __forceinline__ void gemm2(const bf16* __restrict__ wb, int obase, const bf16* xb,
                                      const float* __restrict__ bqs, int g, int c,
                                      f32x4 acc2[2][4]) {
#pragma unroll
  for (int tf = 0; tf < 2; ++tf) {
    const bf16* ab = wb + (obase + tf * 16 + c) * 256 + g * 8;
    bf16x8 afr[8];
#pragma unroll
    for (int ks = 0; ks < 8; ++ks) afr[ks] = *(const bf16x8*)(ab + ks * 32);
#pragma unroll
    for (int ks = 0; ks < 8; ++ks) {
      const bf16* bb = xb + (ks * 4 + g) * QS + c * 8;
#pragma unroll
      for (int nt = 0; nt < 4; ++nt)
        acc2[tf][nt] = MFMA16(afr[ks], *(const bf16x8*)(bb + nt * 128), acc2[tf][nt]);
    }
#pragma unroll
    for (int i = 0; i < 4; ++i) {
      float bq = bqs[obase + tf * 16 + g * 4 + i];
#pragma unroll
      for (int nt = 0; nt < 4; ++nt) acc2[tf][nt][i] += bq;
    }
  }
}

__global__ __launch_bounds__(256, 4) void attn_kernel(
    const float* __restrict__ x, const float* __restrict__ mask, const float* __restrict__ b_proj,
    const char* __restrict__ ws, float* __restrict__ out) {
  extern __shared__ char smem[];
  bf16* xb = (bf16*)(smem + A_OFF);
  bf16* ao = (bf16*)(smem + B_OFF);
  float* outf = (float*)(smem + A_OFF);  // proj staging overlays xb

  const bf16* wqkvb = (const bf16*)(ws + WQKV_OFF);
  const bf16* wprojb = (const bf16*)(ws + WPROJ_OFF);
  const float* biasx = (const float*)(ws + BIAS_OFF);
  const float* bqs = (const float*)(ws + BQKV_OFF);

  const int tid = threadIdx.x;
  const int w = blockIdx.x;
  const int lane = tid & 63;
  const int wave = tid >> 6;  // 0..3
  const int g = lane >> 4;    // 16-lane group
  const int c = lane & 15;

  const float* xw = x + (size_t)w * 12544;

  // ---- stage x -> xb bf16, [cc][n<49][8]; zero pad rows 49,50 of every chunk ----
#pragma unroll
  for (int it = 0; it < 13; ++it) {
    int idx = it * 256 + tid;
    if (idx < 3136) {
      int n = idx >> 6, c4 = (idx & 63) << 2;
      float4 v = ((const float4*)xw)[idx];
      bf16x4 b4;
      b4[0] = (bf16)v.x; b4[1] = (bf16)v.y; b4[2] = (bf16)v.z; b4[3] = (bf16)v.w;
      *(bf16x4*)(xb + ((c4 >> 3) * QS + n * 8 + (c4 & 7))) = b4;
    }
  }
  {
    // 32 chunks x rows {49,50} x 8 elems = 512 elements = 128 bf16x4 stores
    int cc = tid >> 3, e4 = (tid & 7);  // tid<256: cc 0..31, e4 0..7 -> row 49+e4/... 
    // rows 49,50: element offsets 392..407 (16 elems) -> 4 x bf16x4 per chunk
    if ((tid & 7) < 4) {
      bf16x4 z = {};
      *(bf16x4*)(xb + cc * QS + 392 + e4 * 4) = z;
    }
  }
  __syncthreads();

  const float* mk = mask + (size_t)w * 2401;
  const int base = (g & 1) * 32 + c;
  const bool glow = (g < 2);

  // ---- per-head: K-GEMM, Q-GEMM, S^T+softmax->pb, V-GEMM, PV, ao ----
#pragma unroll 1
  for (int hh = 0; hh < 2; ++hh) {
    const int h = wave * 2 + hh;

    bf16x8 kb[4];
    {
      f32x4 acc2[2][4] = {};
      gemm2(wqkvb, 256 + h * 32, xb, bqs, g, c, acc2);
#pragma unroll
      for (int mt = 0; mt < 4; ++mt) kb[mt] = xpose8(acc2[0][mt], acc2[1][mt], base, glow);
    }
    bf16x8 qa[4];
    {
      f32x4 acc2[2][4] = {};
      gemm2(wqkvb, h * 32, xb, bqs, g, c, acc2);
#pragma unroll
      for (int rt = 0; rt < 4; ++rt) qa[rt] = xpose8(acc2[0][rt], acc2[1][rt], base, glow);
    }

    // S^T per column-tile -> softmax -> P fragments (pb)
    const float* bhT = biasx + h * 2401;
    bf16x8 pb[4][2];
#pragma unroll
    for (int nt = 0; nt < 4; ++nt) {
      f32x4 z = {};
      f32x4 sc[4];
#pragma unroll
      for (int mt = 0; mt < 4; ++mt) sc[mt] = MFMA16(kb[mt], qa[nt], z);
      const int n = nt * 16 + c;
      const int nc = n > 48 ? 48 : n;
      const bool nok = (n < 49);
      float p[4][4];
#pragma unroll
      for (int mt = 0; mt < 4; ++mt)
#pragma unroll
        for (int i = 0; i < 4; ++i) {
          int m = mt * 16 + g * 4 + i;
          int mc2 = m > 48 ? 48 : m;
          p[mt][i] = (nok && m < 49) ? (sc[mt][i] + bhT[mc2 * 49 + nc] + mk[nc * 49 + mc2])
                                     : -1e30f;
        }
      float mx = p[0][0];
#pragma unroll
      for (int mt = 0; mt < 4; ++mt)
#pragma unroll
        for (int i = 0; i < 4; ++i) mx = fmaxf(mx, p[mt][i]);
      mx = fmaxf(mx, __shfl_xor(mx, 16));
      mx = fmaxf(mx, __shfl_xor(mx, 32));
      float sum = 0.f;
#pragma unroll
      for (int mt = 0; mt < 4; ++mt)
#pragma unroll
        for (int i = 0; i < 4; ++i) {
          p[mt][i] = __expf(p[mt][i] - mx);
          sum += p[mt][i];
        }
      sum += __shfl_xor(sum, 16);
      sum += __shfl_xor(sum, 32);
      float rinv = nok ? (1.0f / sum) : 0.0f;
#pragma unroll
      for (int mt = 0; mt < 4; ++mt)
#pragma unroll
        for (int i = 0; i < 4; ++i) p[mt][i] *= rinv;
#pragma unroll
      for (int ks = 0; ks < 2; ++ks) {
        bf16x8 f;
#pragma unroll
        for (int j = 0; j < 8; ++j) {
          int src = ((g & 1) * 2 + (j >> 2)) * 16 + c;
          float vA = __shfl(p[2 * ks][j & 3], src);
          float vB = __shfl(p[2 * ks + 1][j & 3], src);
          f[j] = (bf16)(glow ? vA : vB);
        }
        pb[nt][ks] = f;
      }
    }

    // ---- V-GEMM in D[n][o] orientation (A=X, B=W) -> va via row-tile transpose ----
    // (R6-proven orientation: xpose8 pairs TOKEN tiles; mask hits true m.)
    bf16x8 va[2][2];
#pragma unroll
    for (int dt = 0; dt < 2; ++dt) {
      const int o = 512 + h * 32 + dt * 16 + c;
      const bf16* bbw = wqkvb + o * 256 + g * 8;
      bf16x8 bfr[8];
#pragma unroll
      for (int ks = 0; ks < 8; ++ks) bfr[ks] = *(const bf16x8*)(bbw + ks * 32);
      f32x4 acc[4] = {};
#pragma unroll
      for (int ks = 0; ks < 8; ++ks) {
        const bf16* abL = xb + (ks * 4 + g) * QS + c * 8;
#pragma unroll
        for (int mt = 0; mt < 4; ++mt) {
          bf16x8 afr = *(const bf16x8*)(abL + mt * 128);
          acc[mt] = MFMA16(afr, bfr[ks], acc[mt]);
        }
      }
      const float bv = bqs[o];
#pragma unroll
      for (int mt = 0; mt < 4; ++mt) {
        acc[mt][0] += bv; acc[mt][1] += bv; acc[mt][2] += bv; acc[mt][3] += bv;
      }
#pragma unroll
      for (int ks = 0; ks < 2; ++ks) {
        bf16x8 f = xpose8(acc[2 * ks], acc[2 * ks + 1], base, glow);
#pragma unroll
        for (int j = 0; j < 8; ++j) {
          int m = ks * 32 + g * 8 + j;
          if (m >= 49) f[j] = (bf16)0.f;
        }
        va[dt][ks] = f;
      }
    }

    // PV
    f32x4 oacc[2][4] = {};
#pragma unroll
    for (int nt = 0; nt < 4; ++nt)
#pragma unroll
      for (int ks = 0; ks < 2; ++ks)
#pragma unroll
        for (int dt = 0; dt < 2; ++dt)
          oacc[dt][nt] = MFMA16(va[dt][ks], pb[nt][ks], oacc[dt][nt]);

    // attn-out -> ao (wave-private chunk range)
#pragma unroll
    for (int dt = 0; dt < 2; ++dt) {
      int cb = h * 32 + dt * 16 + g * 4;
      int cc = cb >> 3, clow = cb & 7;
#pragma unroll
      for (int nt = 0; nt < 4; ++nt) {
        int n = nt * 16 + c;
        if (n < 49) {
          bf16x4 pk;
          pk[0] = (bf16)oacc[dt][nt][0]; pk[1] = (bf16)oacc[dt][nt][1];
          pk[2] = (bf16)oacc[dt][nt][2]; pk[3] = (bf16)oacc[dt][nt][3];
          *(bf16x4*)(ao + (cc * QS + n * 8 + clow)) = pk;
        }
      }
    }
  }
  __syncthreads();  // ao complete; xb dead -> outf overlay safe

  // ---- proj in two co-halves, staged through region A, coalesced copy out ----
  float4* outw4 = (float4*)(out + (size_t)w * 12544);
  const float4* outf4 = (const float4*)outf;
#pragma unroll
  for (int half = 0; half < 2; ++half) {
#pragma unroll
    for (int tt = 0; tt < 2; ++tt) {
      const int ctl = wave * 2 + tt;  // 0..7
      const int ct = half * 8 + ctl;
      const bf16* bbw = wprojb + (ct * 16 + c) * 256 + g * 8;
      bf16x8 bfr[8];
#pragma unroll
      for (int ks = 0; ks < 8; ++ks) bfr[ks] = *(const bf16x8*)(bbw + ks * 32);
      f32x4 acc[4] = {};
#pragma unroll
      for (int ks = 0; ks < 8; ++ks) {
        const bf16* abL = ao + (ks * 4 + g) * QS + c * 8;
#pragma unroll
        for (int mt = 0; mt < 4; ++mt) {
          bf16x8 afr = *(const bf16x8*)(abL + mt * 128);
          acc[mt] = MFMA16(afr, bfr[ks], acc[mt]);
        }
      }
      float bp = b_proj[ct * 16 + c];
      const int q = ctl * 4 + (c >> 2);
      const int c3 = c & 3;
#pragma unroll
      for (int mt = 0; mt < 4; ++mt) {
#pragma unroll
        for (int i = 0; i < 4; ++i) {
          int n = mt * 16 + g * 4 + i;
          if (n < 49) outf[n * 128 + ((q ^ (n & 7)) << 2) + c3] = acc[mt][i] + bp;
        }
      }
    }
    __syncthreads();
#pragma unroll
    for (int it = 0; it < 7; ++it) {
      int f = it * 256 + tid;
      if (f < 1568) {
        int n = f >> 5, q2 = f & 31;
        outw4[n * 64 + half * 32 + q2] = outf4[n * 32 + (q2 ^ (n & 7))];
      }
    }
    __syncthreads();
  }
}

extern "C" void kernel_launch(void* const* d_in, const int* in_sizes, int n_in,
                              void* d_out, int out_size, void* d_ws, size_t ws_size,
                              hipStream_t stream) {
  const float* x = (const float*)d_in[0];
  const float* mask = (const float*)d_in[1];
  const float* w_qkv = (const float*)d_in[2];
  const float* b_qkv = (const float*)d_in[3];
  const float* w_proj = (const float*)d_in[4];
  const float* b_proj = (const float*)d_in[5];
  const float* bias_table = (const float*)d_in[6];
  const int* rel_index = (const int*)d_in[7];
  float* out = (float*)d_out;
  char* ws = (char*)d_ws;

  (void)in_sizes; (void)n_in; (void)out_size; (void)ws_size;

  hipFuncSetAttribute((const void*)attn_kernel, hipFuncAttributeMaxDynamicSharedMemorySize,
                      LDS_BYTES);

  prep_kernel<<<1103, 256, 0, stream>>>(w_qkv, b_qkv, w_proj, bias_table, rel_index, ws);
  attn_kernel<<<4096, 256, LDS_BYTES, stream>>>(x, mask, b_proj, ws, out);
}

// Round 9
// 443.907 us; speedup vs baseline: 2.2992x; 2.2992x over previous
//
#include <hip/hip_runtime.h>
#include <hip/hip_bf16.h>

typedef __bf16 bf16;
typedef bf16 bf16x4 __attribute__((ext_vector_type(4)));
typedef bf16 bf16x8 __attribute__((ext_vector_type(8)));
typedef float f32x4 __attribute__((ext_vector_type(4)));

#define MFMA16(a, b, c) __builtin_amdgcn_mfma_f32_16x16x32_bf16((a), (b), (c), 0, 0, 0)

constexpr float kScale = 0.17677669529663687f;  // 1/sqrt(32)

// ---- workspace offsets (bytes) ----
constexpr int WQKV_OFF = 0;        // bf16[768*256]
constexpr int WPROJ_OFF = 393216;  // bf16[256*256]
constexpr int BIAS_OFF = 524288;   // f32[8][49 m][49 n]  (transposed bias)
constexpr int BQKV_OFF = 601120;   // f32[768]

// ---- LDS layout (bytes) ----
// xb: bf16 [32 cc][QS] = 26240 B  (x staging; later attn-out rows n<49)
// qk: bf16 [64 oc][QS] = 52480 B  (Q o<256 scaled, K; row 49 zeroed)
//     after attention: f32 outf[49][64 float4] (swizzled) = 50176 B
constexpr int QK_OFF = 26240;
constexpr int QS = 410;  // chunk stride in elems; dword-stride 205 (odd) => debanked
constexpr int LDS_BYTES = 78720;

__global__ void prep_kernel(const float* __restrict__ w_qkv, const float* __restrict__ b_qkv,
                            const float* __restrict__ w_proj, const float* __restrict__ bias_table,
                            const int* __restrict__ rel_index, char* __restrict__ ws) {
  int i = blockIdx.x * 256 + threadIdx.x;
  bf16* wqkvb = (bf16*)(ws + WQKV_OFF);
  bf16* wprojb = (bf16*)(ws + WPROJ_OFF);
  float* biasx = (float*)(ws + BIAS_OFF);
  float* bqs = (float*)(ws + BQKV_OFF);
  if (i < 196608) {
    float v = w_qkv[i];
    if (i < 65536) v *= kScale;  // q rows (o<256): fold scale
    wqkvb[i] = (bf16)v;
  } else if (i < 262144) {
    int j = i - 196608;
    wprojb[j] = (bf16)w_proj[j];
  } else if (i < 281352) {
    int j = i - 262144;  // 8*2401, layout [h][m][n]
    int h = j / 2401, nm = j - h * 2401;
    int mm = nm / 49, nn = nm - mm * 49;
    biasx[j] = bias_table[rel_index[nn * 49 + mm] * 8 + h];  // bias[h][nn][mm]
  } else if (i < 282120) {
    int j = i - 281352;
    bqs[j] = b_qkv[j] * (j < 256 ? kScale : 1.0f);
  }
}

// Shuffle-transpose: treats (lo,hi) as a 32-row pair; f[j] = Pair[row32=g*8+j][col=c].
__device__ __forceinline__ bf16x8 xpose8(f32x4 lo, f32x4 hi, int base, bool glow) {
  bf16x8 f;
#pragma unroll
  for (int i = 0; i < 4; ++i) {
    float a0 = __shfl(lo[i], base);
    float a1 = __shfl(lo[i], base + 16);
    float b0 = __shfl(hi[i], base);
    float b1 = __shfl(hi[i], base + 16);
    f[i] = (bf16)(glow ? a0 : b0);
    f[i + 4] = (bf16)(glow ? a1 : b1);
  }
  return f;
}

__global__ __launch_bounds__(256, 2) void attn_kernel(
    const float* __restrict__ x, const float* __restrict__ mask, const float* __restrict__ b_proj,
    const char* __restrict__ ws, float* __restrict__ out) {
  extern __shared__ char smem[];
  bf16* xb = (bf16*)(smem);
  bf16* qk = (bf16*)(smem + QK_OFF);
  float* outf = (float*)(smem + QK_OFF);  // overlays qk after attention

  const bf16* wqkvb = (const bf16*)(ws + WQKV_OFF);
  const bf16* wprojb = (const bf16*)(ws + WPROJ_OFF);
  const float* biasx = (const float*)(ws + BIAS_OFF);
  const float* bqs = (const float*)(ws + BQKV_OFF);

  const int tid = threadIdx.x;
  const int w = blockIdx.x;
  const int lane = tid & 63;
  const int wave = tid >> 6;  // 0..3
  const int g = lane >> 4;    // 16-lane group
  const int c = lane & 15;

  const float* xw = x + (size_t)w * 12544;

  // ---- stage x -> xb bf16, [cc][n<49][8] ----
#pragma unroll
  for (int it = 0; it < 13; ++it) {
    int idx = it * 256 + tid;
    if (idx < 3136) {
      int n = idx >> 6, c4 = (idx & 63) << 2;
      float4 v = ((const float4*)xw)[idx];
      bf16x4 b4;
      b4[0] = (bf16)v.x; b4[1] = (bf16)v.y; b4[2] = (bf16)v.z; b4[3] = (bf16)v.w;
      *(bf16x4*)(xb + ((c4 >> 3) * QS + n * 8 + (c4 & 7))) = b4;
    }
  }
  __syncthreads();

  // ---- GEMM1 (Q,K -> qk LDS): 2 quads of 4 o-tiles; k-step outermost ----
  for (int qd = 0; qd < 2; ++qd) {
    const int ot0 = wave * 8 + qd * 4;
    f32x4 acc[4][4] = {};  // [tile][nt]
#pragma unroll
    for (int ks = 0; ks < 8; ++ks) {
      bf16x8 b[4];
#pragma unroll
      for (int nt = 0; nt < 4; ++nt)
        b[nt] = *(const bf16x8*)(xb + (ks * 4 + g) * QS + c * 8 + nt * 128);
      bf16x8 a[4];
#pragma unroll
      for (int t = 0; t < 4; ++t)
        a[t] = *(const bf16x8*)(wqkvb + ((ot0 + t) * 16 + c) * 256 + ks * 32 + g * 8);
#pragma unroll
      for (int t = 0; t < 4; ++t)
#pragma unroll
        for (int nt = 0; nt < 4; ++nt) acc[t][nt] = MFMA16(a[t], b[nt], acc[t][nt]);
    }
#pragma unroll
    for (int t = 0; t < 4; ++t) {
      const int ot = ot0 + t;
      const int ob = ot * 16 + g * 4;
      const float bq0 = bqs[ob], bq1 = bqs[ob + 1], bq2 = bqs[ob + 2], bq3 = bqs[ob + 3];
      const int oc = ob >> 3, olow = ob & 7;
#pragma unroll
      for (int nt = 0; nt < 4; ++nt) {
        int n = nt * 16 + c;
        if (n < 50) {
          bool ok = (n < 49);
          bf16x4 pk;
          pk[0] = ok ? (bf16)(acc[t][nt][0] + bq0) : (bf16)0.f;
          pk[1] = ok ? (bf16)(acc[t][nt][1] + bq1) : (bf16)0.f;
          pk[2] = ok ? (bf16)(acc[t][nt][2] + bq2) : (bf16)0.f;
          pk[3] = ok ? (bf16)(acc[t][nt][3] + bq3) : (bf16)0.f;
          *(bf16x4*)(qk + (oc * QS + n * 8 + olow)) = pk;
        }
      }
    }
  }

  const int base = (g & 1) * 32 + c;
  const bool glow = (g < 2);

  // ---- V-GEMM quad (D[n][o], A=X shared, B=W per tile) -> va registers ----
  bf16x8 va[2][2][2];  // [hh][dt][ks]
  {
    f32x4 acc[4][4] = {};  // [tile][mt]
#pragma unroll
    for (int ks = 0; ks < 8; ++ks) {
      bf16x8 a[4];
#pragma unroll
      for (int mt = 0; mt < 4; ++mt)
        a[mt] = *(const bf16x8*)(xb + (ks * 4 + g) * QS + c * 8 + mt * 128);
      bf16x8 bw[4];
#pragma unroll
      for (int t = 0; t < 4; ++t)
        bw[t] = *(const bf16x8*)(wqkvb + (512 + (wave * 4 + t) * 16 + c) * 256 + ks * 32 + g * 8);
#pragma unroll
      for (int t = 0; t < 4; ++t)
#pragma unroll
        for (int mt = 0; mt < 4; ++mt) acc[t][mt] = MFMA16(a[mt], bw[t], acc[t][mt]);
    }
#pragma unroll
    for (int t = 0; t < 4; ++t) {
      const int o = 512 + (wave * 4 + t) * 16 + c;
      const float bv = bqs[o];
#pragma unroll
      for (int mt = 0; mt < 4; ++mt) {
        acc[t][mt][0] += bv; acc[t][mt][1] += bv; acc[t][mt][2] += bv; acc[t][mt][3] += bv;
      }
#pragma unroll
      for (int ks = 0; ks < 2; ++ks) {
        bf16x8 f = xpose8(acc[t][2 * ks], acc[t][2 * ks + 1], base, glow);
#pragma unroll
        for (int j = 0; j < 8; ++j) {
          int m = ks * 32 + g * 8 + j;
          if (m >= 49) f[j] = (bf16)0.f;
        }
        va[t >> 1][t & 1][ks] = f;
      }
    }
  }
  __syncthreads();  // all xb reads done; qk fully written

  // ---- attention (S^T): wave -> heads 2w, 2w+1; gathers pipelined ----
  const float* mk = mask + (size_t)w * 2401;

#pragma unroll
  for (int hh = 0; hh < 2; ++hh) {
    const int h = wave * 2 + hh;
    const float* bhT = biasx + h * 2401;

    bf16x8 qa[4], kb[4];
#pragma unroll
    for (int rt = 0; rt < 4; ++rt) {
      int n = rt * 16 + c; n = n > 49 ? 49 : n;  // row 49 = zeros
      qa[rt] = *(const bf16x8*)(qk + ((h * 4 + g) * QS + n * 8));
    }
#pragma unroll
    for (int mt = 0; mt < 4; ++mt) {
      int m = mt * 16 + c; m = m > 49 ? 49 : m;
      kb[mt] = *(const bf16x8*)(qk + ((32 + h * 4 + g) * QS + m * 8));
    }

    // S^T[m][n] all 16 MFMAs
    f32x4 s[4][4] = {};  // [mt][nt]
#pragma unroll
    for (int mt = 0; mt < 4; ++mt)
#pragma unroll
      for (int nt = 0; nt < 4; ++nt) s[mt][nt] = MFMA16(kb[mt], qa[nt], s[mt][nt]);

    float bi[16], mi[16];
#define GATHER(NT)                                              \
    {                                                           \
      const int n_ = (NT) * 16 + c;                             \
      const int nc_ = n_ > 48 ? 48 : n_;                        \
      _Pragma("unroll") for (int mt = 0; mt < 4; ++mt)          \
        _Pragma("unroll") for (int i = 0; i < 4; ++i) {         \
          int m_ = mt * 16 + g * 4 + i;                         \
          int mc_ = m_ > 48 ? 48 : m_;                          \
          bi[mt * 4 + i] = bhT[mc_ * 49 + nc_];                 \
          mi[mt * 4 + i] = mk[nc_ * 49 + mc_];                  \
        }                                                       \
    }

    GATHER(0);
    f32x4 oacc[2][4] = {};
#pragma unroll
    for (int nt = 0; nt < 4; ++nt) {
      const int n = nt * 16 + c;
      const bool nok = (n < 49);
      // softmax (no max-subtract: |vals| << 88)
      float p[4][4];
      float sum = 0.f;
#pragma unroll
      for (int mt = 0; mt < 4; ++mt)
#pragma unroll
        for (int i = 0; i < 4; ++i) {
          int m = mt * 16 + g * 4 + i;
          float v = s[mt][nt][i] + bi[mt * 4 + i] + mi[mt * 4 + i];
          float pv = (nok && m < 49) ? __expf(v) : 0.f;
          p[mt][i] = pv;
          sum += pv;
        }
      sum += __shfl_xor(sum, 16);
      sum += __shfl_xor(sum, 32);
      float rinv = nok ? (1.0f / sum) : 0.0f;
#pragma unroll
      for (int mt = 0; mt < 4; ++mt)
#pragma unroll
        for (int i = 0; i < 4; ++i) p[mt][i] *= rinv;

      if (nt < 3) {  // prefetch next column-tile's bias/mask under shuffles+PV
        if (nt == 0) GATHER(1);
        if (nt == 1) GATHER(2);
        if (nt == 2) GATHER(3);
      }

      // P^T fragments via register shuffle, then PV
#pragma unroll
      for (int ks = 0; ks < 2; ++ks) {
        bf16x8 f;
#pragma unroll
        for (int j = 0; j < 8; ++j) {
          int src = ((g & 1) * 2 + (j >> 2)) * 16 + c;
          float vA = __shfl(p[2 * ks][j & 3], src);
          float vB = __shfl(p[2 * ks + 1][j & 3], src);
          f[j] = (bf16)(glow ? vA : vB);
        }
#pragma unroll
        for (int dt = 0; dt < 2; ++dt) oacc[dt][nt] = MFMA16(va[hh][dt][ks], f, oacc[dt][nt]);
      }
    }
#undef GATHER

    // attn-out -> xb rows n<49 (xb x-content dead; barrier above separates)
#pragma unroll
    for (int dt = 0; dt < 2; ++dt) {
      int cb = h * 32 + dt * 16 + g * 4;
      int cc = cb >> 3, clow = cb & 7;
#pragma unroll
      for (int nt = 0; nt < 4; ++nt) {
        int n = nt * 16 + c;
        if (n < 49) {
          bf16x4 pk;
          pk[0] = (bf16)oacc[dt][nt][0]; pk[1] = (bf16)oacc[dt][nt][1];
          pk[2] = (bf16)oacc[dt][nt][2]; pk[3] = (bf16)oacc[dt][nt][3];
          *(bf16x4*)(xb + (cc * QS + n * 8 + clow)) = pk;
        }
      }
    }
  }
  __syncthreads();  // attn-out complete; qk dead -> outf overlay safe

  // ---- proj quad (A=attn-out in xb, B=Wp per tile) -> outf (swizzled) ----
  {
    f32x4 acc[4][4] = {};  // [tile][mt]
#pragma unroll
    for (int ks = 0; ks < 8; ++ks) {
      bf16x8 a[4];
#pragma unroll
      for (int mt = 0; mt < 4; ++mt)
        a[mt] = *(const bf16x8*)(xb + (ks * 4 + g) * QS + c * 8 + mt * 128);
      bf16x8 bw[4];
#pragma unroll
      for (int t = 0; t < 4; ++t)
        bw[t] = *(const bf16x8*)(wprojb + ((wave * 4 + t) * 16 + c) * 256 + ks * 32 + g * 8);
#pragma unroll
      for (int t = 0; t < 4; ++t)
#pragma unroll
        for (int mt = 0; mt < 4; ++mt) acc[t][mt] = MFMA16(a[mt], bw[t], acc[t][mt]);
    }
#pragma unroll
    for (int t = 0; t < 4; ++t) {
      const int ct = wave * 4 + t;
      const float bp = b_proj[ct * 16 + c];
      const int co = ct * 16 + c, q = co >> 2, c3 = co & 3;
#pragma unroll
      for (int mt = 0; mt < 4; ++mt) {
#pragma unroll
        for (int i = 0; i < 4; ++i) {
          int n = mt * 16 + g * 4 + i;
          if (n < 49) outf[n * 256 + ((q ^ (n & 15)) << 2) + c3] = acc[t][mt][i] + bp;
        }
      }
    }
  }
  __syncthreads();

  // ---- coalesced copy LDS -> global (full float4 lines) ----
  float4* outw4 = (float4*)(out + (size_t)w * 12544);
  const float4* outf4 = (const float4*)outf;
#pragma unroll
  for (int it = 0; it < 13; ++it) {
    int f = it * 256 + tid;
    if (f < 3136) {
      int n = f >> 6, q = f & 63;
      outw4[f] = outf4[n * 64 + (q ^ (n & 15))];
    }
  }
}

extern "C" void kernel_launch(void* const* d_in, const int* in_sizes, int n_in,
                              void* d_out, int out_size, void* d_ws, size_t ws_size,
                              hipStream_t stream) {
  const float* x = (const float*)d_in[0];
  const float* mask = (const float*)d_in[1];
  const float* w_qkv = (const float*)d_in[2];
  const float* b_qkv = (const float*)d_in[3];
  const float* w_proj = (const float*)d_in[4];
  const float* b_proj = (const float*)d_in[5];
  const float* bias_table = (const float*)d_in[6];
  const int* rel_index = (const int*)d_in[7];
  float* out = (float*)d_out;
  char* ws = (char*)d_ws;

  (void)in_sizes; (void)n_in; (void)out_size; (void)ws_size;

  hipFuncSetAttribute((const void*)attn_kernel, hipFuncAttributeMaxDynamicSharedMemorySize,
                      LDS_BYTES);

  prep_kernel<<<1103, 256, 0, stream>>>(w_qkv, b_qkv, w_proj, bias_table, rel_index, ws);
  attn_kernel<<<4096, 256, LDS_BYTES, stream>>>(x, mask, b_proj, ws, out);
}